// Round 4
// baseline (29.959 us; speedup 1.0000x reference)
//
#include <hip/hip_runtime.h>

// Problem constants (from reference):
//   x: (PH*PW=49, B=2, C=3, 256, 256) fp32
//   out: (2, 3, 1024, 1024) fp32
//   out[b,c,h,w] = max over patches (i,j) with i*128<=h<i*128+256,
//                  j*128<=w<j*128+256 of x[i*7+j, b, c, h-i*128, w-j*128]
#define PATCH   256
#define STRIDEP 128
#define Bn      2
#define Cn      3
#define Hn      1024
#define Wn      1024
#define PHn     7
#define PWn     7

typedef float v4f __attribute__((ext_vector_type(4)));

// One thread per 16 output floats (4x float4).
// Total chunks: 2*3*1024*1024/16 = 393216 -> 1536 blocks of 256.
// 1536 blocks = 6 blocks/CU on 256 CUs, ALL co-resident (cap is 8/CU at 4
// waves/block) -> single scheduling round, no tail quantization.
__global__ __launch_bounds__(256) void unpatch_max_kernel(
    const float* __restrict__ x, float* __restrict__ out)
{
    const int gid = blockIdx.x * blockDim.x + threadIdx.x;
    const int W16 = Wn / 16;                // 64 chunks per row
    // decompose gid -> (bc, h, w16)
    const int w16  = gid & (W16 - 1);       // pow2
    const int rest = gid >> 6;
    const int h    = rest & (Hn - 1);       // pow2; wave-uniform
    const int bc   = rest >> 10;            // b*Cn + c, in [0,6)
    const int w    = w16 << 4;

    // covering patch rows/cols: {floor(h/128)-1, floor(h/128)} clamped to
    // [0,6]. A 16-aligned 16-float span never straddles a 128 boundary, so
    // the j-set is uniform across the whole chunk.
    const int hi = h >> 7;
    const int i1 = hi < PHn ? hi : (PHn - 1);
    const int i0 = hi > 0 ? hi - 1 : 0;
    const int wi = w >> 7;
    const int j1 = wi < PWn ? wi : (PWn - 1);
    const int j0 = wi > 0 ? wi - 1 : 0;

    v4f m0 = (v4f){-INFINITY, -INFINITY, -INFINITY, -INFINITY};
    v4f m1 = m0, m2 = m0, m3 = m0;

    #pragma unroll 2
    for (int i = i0; i <= i1; ++i) {
        const int ph = h - i * STRIDEP;     // in [0,256)
        #pragma unroll 2
        for (int j = j0; j <= j1; ++j) {
            const int pw  = w - j * STRIDEP;             // in [0,240], 16-aligned
            const int idx = i * PWn + j;                 // patch index
            const float* p = x +
                ((size_t)(idx * (Bn * Cn) + bc) * PATCH + ph) * PATCH + pw;
            const v4f v0 = *reinterpret_cast<const v4f*>(p);
            const v4f v1 = *reinterpret_cast<const v4f*>(p + 4);
            const v4f v2 = *reinterpret_cast<const v4f*>(p + 8);
            const v4f v3 = *reinterpret_cast<const v4f*>(p + 12);
            m0 = __builtin_elementwise_max(m0, v0);
            m1 = __builtin_elementwise_max(m1, v1);
            m2 = __builtin_elementwise_max(m2, v2);
            m3 = __builtin_elementwise_max(m3, v3);
        }
    }

    v4f* outp = reinterpret_cast<v4f*>(out + (size_t)gid * 16);
    __builtin_nontemporal_store(m0, outp);
    __builtin_nontemporal_store(m1, outp + 1);
    __builtin_nontemporal_store(m2, outp + 2);
    __builtin_nontemporal_store(m3, outp + 3);
}

extern "C" void kernel_launch(void* const* d_in, const int* in_sizes, int n_in,
                              void* d_out, int out_size, void* d_ws, size_t ws_size,
                              hipStream_t stream)
{
    const float* x = (const float*)d_in[0];
    float* out = (float*)d_out;

    const int total16 = (Bn * Cn * Hn * Wn) / 16;  // 393216
    const int block   = 256;
    const int grid    = total16 / block;           // 1536
    unpatch_max_kernel<<<grid, block, 0, stream>>>(x, out);
}

// Round 5
// 21.639 us; speedup vs baseline: 1.3845x; 1.3845x over previous
//
#include <hip/hip_runtime.h>

// Problem constants (from reference):
//   x: (PH*PW=49, B=2, C=3, 256, 256) fp32
//   out: (2, 3, 1024, 1024) fp32
//   out[b,c,h,w] = max over patches (i,j) with i*128<=h<i*128+256,
//                  j*128<=w<j*128+256 of x[i*7+j, b, c, h-i*128, w-j*128]
#define PATCH   256
#define STRIDEP 128
#define Bn      2
#define Cn      3
#define Hn      1024
#define Wn      1024
#define PHn     7
#define PWn     7

typedef float v4f __attribute__((ext_vector_type(4)));

// One float4 per thread PER CHUNK, K=3 chunks per thread, chunks separated by
// the full grid span (524288 float4 = 512 output rows). Lane stride stays
// 16 B (contiguous 1 KB per wave-instruction; R4 showed 64 B lane stride
// costs 35%). 2048 blocks = 8 blocks/CU, all co-resident in one round; the
// 3 distant chunks average out the 1/2/4-load border imbalance per thread.
#define KCHUNK  3
#define NBLK    2048
#define CHUNK_STRIDE (NBLK * 256)   // 524288 float4s

__global__ __launch_bounds__(256) void unpatch_max_kernel(
    const float* __restrict__ x, float* __restrict__ out)
{
    const int gid = blockIdx.x * blockDim.x + threadIdx.x;

    #pragma unroll
    for (int k = 0; k < KCHUNK; ++k) {
        const int cid = gid + k * CHUNK_STRIDE;
        // decompose cid -> (bc, h, w4)
        const int w4   = cid & 255;          // 256 float4 per row
        const int rest = cid >> 8;
        const int h    = rest & (Hn - 1);    // wave-uniform
        const int bc   = rest >> 10;         // b*Cn + c, in [0,6)
        const int w    = w4 << 2;

        const int hi = h >> 7;
        const int i1 = hi < PHn ? hi : (PHn - 1);
        const int i0 = hi > 0 ? hi - 1 : 0;
        const int wi = w >> 7;
        const int j1 = wi < PWn ? wi : (PWn - 1);
        const int j0 = wi > 0 ? wi - 1 : 0;

        v4f m = (v4f){-INFINITY, -INFINITY, -INFINITY, -INFINITY};

        #pragma unroll 2
        for (int i = i0; i <= i1; ++i) {
            const int ph = h - i * STRIDEP;              // in [0,256)
            #pragma unroll 2
            for (int j = j0; j <= j1; ++j) {
                const int pw  = w - j * STRIDEP;         // in [0,252], 4-aligned
                const int idx = i * PWn + j;             // patch index
                const float* p = x +
                    ((size_t)(idx * (Bn * Cn) + bc) * PATCH + ph) * PATCH + pw;
                m = __builtin_elementwise_max(m, *reinterpret_cast<const v4f*>(p));
            }
        }

        __builtin_nontemporal_store(
            m, reinterpret_cast<v4f*>(out + (size_t)cid * 4));
    }
}

extern "C" void kernel_launch(void* const* d_in, const int* in_sizes, int n_in,
                              void* d_out, int out_size, void* d_ws, size_t ws_size,
                              hipStream_t stream)
{
    const float* x = (const float*)d_in[0];
    float* out = (float*)d_out;
    unpatch_max_kernel<<<NBLK, 256, 0, stream>>>(x, out);
}